// Round 1
// baseline (17188.976 us; speedup 1.0000x reference)
//
#include <hip/hip_runtime.h>

// LSTM T=2048 B=32 DIN=512 H=512.
// Strategy: persistent 32-WG scan kernel; weights (Wx,Wh) resident in VGPRs as
// MFMA B-fragments; per-step cross-WG h exchange via LLC with flag sync.
// Output layout: [h (32*512) | c (32*512) | outs (2048*32*512)] f32.

#define TT 2048
#define BB 32
#define HH 512
#define NWG 32

typedef __attribute__((ext_vector_type(8))) short short8;
typedef __attribute__((ext_vector_type(4))) float fv4;
typedef __attribute__((ext_vector_type(2))) float fv2;
typedef __attribute__((ext_vector_type(4))) unsigned short usv4;

__device__ __forceinline__ unsigned short f2bf(float f) {
  unsigned u = __builtin_bit_cast(unsigned, f);
  u += 0x7fffu + ((u >> 16) & 1u);   // RNE (inputs finite)
  return (unsigned short)(u >> 16);
}
__device__ __forceinline__ float sigm(float x) { return 1.f / (1.f + __expf(-x)); }
__device__ __forceinline__ float tanhfast(float x) { return 1.f - 2.f / (__expf(2.f * x) + 1.f); }

// ---- prologue: pack transposed bf16 weights, summed bias, h(0), flags ----
__global__ void pack_kernel(
    const float* __restrict__ h0,
    const float* __restrict__ Wii, const float* __restrict__ bii,
    const float* __restrict__ Whi, const float* __restrict__ bhi,
    const float* __restrict__ Wif, const float* __restrict__ bif,
    const float* __restrict__ Whf, const float* __restrict__ bhf,
    const float* __restrict__ Wig, const float* __restrict__ big,
    const float* __restrict__ Whg, const float* __restrict__ bhg,
    const float* __restrict__ Wio, const float* __restrict__ bio,
    const float* __restrict__ Who, const float* __restrict__ bho,
    unsigned short* __restrict__ WhT, unsigned short* __restrict__ WxT,
    float* __restrict__ bsum, unsigned short* __restrict__ hbuf,
    int* __restrict__ flags)
{
  int idx = blockIdx.x * 256 + threadIdx.x;
  if (idx < 2048 * 512) {                 // WhT/WxT: row r = gate*512+unit, col k
    int r = idx >> 9, k = idx & 511;
    int g = r >> 9, j = r & 511;
    const float* Wh_ = (g == 0) ? Whi : (g == 1) ? Whf : (g == 2) ? Whg : Who;
    const float* Wx_ = (g == 0) ? Wii : (g == 1) ? Wif : (g == 2) ? Wig : Wio;
    WhT[idx] = f2bf(Wh_[k * 512 + j]);
    WxT[idx] = f2bf(Wx_[k * 512 + j]);
  } else {
    int r2 = idx - 2048 * 512;
    if (r2 < 2048) {
      int g = r2 >> 9, j = r2 & 511;
      const float* bi_ = (g == 0) ? bii : (g == 1) ? bif : (g == 2) ? big : bio;
      const float* bh_ = (g == 0) ? bhi : (g == 1) ? bhf : (g == 2) ? bhg : bho;
      bsum[r2] = bi_[j] + bh_[j];
    } else if (r2 < 2048 + 16384) {
      int m = r2 - 2048;
      hbuf[m] = f2bf(h0[m]);              // parity-0 h buffer = h(0)
    } else if (r2 < 2048 + 16384 + NWG) {
      flags[r2 - 2048 - 16384] = 0;       // flags[w]=s  <=>  h(s) slice written
    }
  }
}

// ---- persistent scan ----
__global__ __launch_bounds__(256, 1) void lstm_scan(
    const float* __restrict__ xs, const float* __restrict__ c0,
    const unsigned short* __restrict__ WhT, const unsigned short* __restrict__ WxT,
    const float* __restrict__ bsum,
    unsigned short* __restrict__ hbuf, int* __restrict__ flags,
    float* __restrict__ out)
{
  __shared__ unsigned short xt[BB][520];  // x_t bf16, pad 8 (row 1040B: 16B-aligned, 65*16B -> uniform bank quads)
  __shared__ float gl[4][BB][16];         // gate preacts exchange

  const int tid = threadIdx.x;
  const int w = tid >> 6;                 // wave = gate (i,f,g,o)
  const int lane = tid & 63;
  const int n = lane & 15;                // MFMA n / A-row m
  const int q = lane >> 4;                // quad
  const int wg = blockIdx.x;
  const int j0 = wg * 16;                 // owned hidden-unit slice

  // B-fragments resident in VGPRs for all 2048 steps (64+64 VGPRs/lane).
  short8 whf[16], wxf[16];
  {
    const unsigned base = (unsigned)(w * 512 + j0 + n) * 512u + (unsigned)q * 8u;
#pragma unroll
    for (int kc = 0; kc < 16; ++kc) {
      whf[kc] = *(const short8*)(WhT + base + kc * 32);
      wxf[kc] = *(const short8*)(WxT + base + kc * 32);
    }
  }

  // elementwise ownership: thread -> (b, jl), units jl, jl+1 (jl even)
  const int bE = (2 * tid) >> 4;
  const int jlE = (2 * tid) & 15;
  float c_st[2], hv[2], bias0[2], bias1[2], bias2[2], bias3[2];
#pragma unroll
  for (int e = 0; e < 2; ++e) {
    c_st[e] = c0[bE * HH + j0 + jlE + e];
    bias0[e] = bsum[0 * 512 + j0 + jlE + e];
    bias1[e] = bsum[1 * 512 + j0 + jlE + e];
    bias2[e] = bsum[2 * 512 + j0 + jlE + e];
    bias3[e] = bsum[3 * 512 + j0 + jlE + e];
    hv[e] = 0.f;
  }

  // stage x(0): coalesced f32 loads -> bf16 -> LDS
#pragma unroll
  for (int i = 0; i < 16; ++i) {
    int f = i * 1024 + tid * 4;
    fv4 v = *(const fv4*)(xs + f);
    int r = f >> 9, cc = f & 511;
    usv4 bv = { f2bf(v[0]), f2bf(v[1]), f2bf(v[2]), f2bf(v[3]) };
    *(usv4*)&xt[r][cc] = bv;
  }

#pragma unroll 1
  for (int t = 0; t < TT; ++t) {
    // ---- wait for h(t) from all WGs ----
    if (tid < NWG) {
      while (__hip_atomic_load(&flags[tid], __ATOMIC_RELAXED, __HIP_MEMORY_SCOPE_AGENT) < t)
        __builtin_amdgcn_s_sleep(1);
    }
    __syncthreads();                                   // also covers x-stage ds_writes
    __builtin_amdgcn_fence(__ATOMIC_ACQUIRE, "agent"); // invalidate L1/L2 -> read fresh LLC

    const unsigned short* hb = hbuf + (t & 1) * (BB * HH);
    fv4 acc0 = {0.f, 0.f, 0.f, 0.f};   // batch rows 0..15
    fv4 acc1 = {0.f, 0.f, 0.f, 0.f};   // batch rows 16..31

#pragma unroll
    for (int ch = 0; ch < 4; ++ch) {
      short8 ha0[4], ha1[4];
      // issue h A-frag loads (LLC), then hide latency under x-side MFMAs
#pragma unroll
      for (int cc = 0; cc < 4; ++cc) {
        const int kc = ch * 4 + cc;
        ha0[cc] = *(const short8*)(hb + n * HH + kc * 32 + q * 8);
        ha1[cc] = *(const short8*)(hb + (16 + n) * HH + kc * 32 + q * 8);
      }
#pragma unroll
      for (int cc = 0; cc < 4; ++cc) {
        const int kc = ch * 4 + cc;
        short8 a0 = *(const short8*)&xt[n][kc * 32 + q * 8];
        short8 a1 = *(const short8*)&xt[16 + n][kc * 32 + q * 8];
        acc0 = __builtin_amdgcn_mfma_f32_16x16x32_bf16(a0, wxf[kc], acc0, 0, 0, 0);
        acc1 = __builtin_amdgcn_mfma_f32_16x16x32_bf16(a1, wxf[kc], acc1, 0, 0, 0);
      }
#pragma unroll
      for (int cc = 0; cc < 4; ++cc) {
        const int kc = ch * 4 + cc;
        acc0 = __builtin_amdgcn_mfma_f32_16x16x32_bf16(ha0[cc], whf[kc], acc0, 0, 0, 0);
        acc1 = __builtin_amdgcn_mfma_f32_16x16x32_bf16(ha1[cc], whf[kc], acc1, 0, 0, 0);
      }
    }

    // ---- exchange gate preacts: D layout col=lane&15, row=quad*4+reg ----
#pragma unroll
    for (int r = 0; r < 4; ++r) {
      gl[w][q * 4 + r][n] = acc0[r];
      gl[w][16 + q * 4 + r][n] = acc1[r];
    }
    __syncthreads();

    // ---- elementwise LSTM cell, c in registers ----
    {
      fv2 gi = *(const fv2*)&gl[0][bE][jlE];
      fv2 gf = *(const fv2*)&gl[1][bE][jlE];
      fv2 gg = *(const fv2*)&gl[2][bE][jlE];
      fv2 go = *(const fv2*)&gl[3][bE][jlE];
      float oo[2];
#pragma unroll
      for (int e = 0; e < 2; ++e) {
        float ig = sigm(gi[e] + bias0[e]);
        float fg = sigm(gf[e] + bias1[e]);
        float gv = tanhfast(gg[e] + bias2[e]);
        float og = sigm(go[e] + bias3[e]);
        float cn = fg * c_st[e] + ig * gv;
        c_st[e] = cn;
        hv[e] = og * tanhfast(cn);
        oo[e] = og;
      }
      fv2 ov = {oo[0], oo[1]};
      *(fv2*)(out + 32768 + (size_t)t * 16384 + bE * 512 + j0 + jlE) = ov;
      unsigned hp = (unsigned)f2bf(hv[0]) | ((unsigned)f2bf(hv[1]) << 16);
      *(unsigned*)(hbuf + ((t + 1) & 1) * (BB * HH) + bE * HH + j0 + jlE) = hp;
    }
    __syncthreads();   // drains all waves' h stores (vmcnt0 before s_barrier)
    if (tid == 0)      // RELEASE: wbl2 -> LLC, then flag visible device-wide
      __hip_atomic_store(&flags[wg], t + 1, __ATOMIC_RELEASE, __HIP_MEMORY_SCOPE_AGENT);

    // ---- prefetch/stage x(t+1) while others catch up ----
    if (t + 1 < TT) {
      const float* xsrc = xs + (size_t)(t + 1) * 16384;
#pragma unroll
      for (int i = 0; i < 16; ++i) {
        int f = i * 1024 + tid * 4;
        fv4 v = *(const fv4*)(xsrc + f);
        int r = f >> 9, cc = f & 511;
        usv4 bv = { f2bf(v[0]), f2bf(v[1]), f2bf(v[2]), f2bf(v[3]) };
        *(usv4*)&xt[r][cc] = bv;
      }
    }
  }

  // final h, c (f32)
  {
    fv2 hvv = {hv[0], hv[1]};
    fv2 cvv = {c_st[0], c_st[1]};
    *(fv2*)(out + bE * 512 + j0 + jlE) = hvv;
    *(fv2*)(out + 16384 + bE * 512 + j0 + jlE) = cvv;
  }
}

extern "C" void kernel_launch(void* const* d_in, const int* in_sizes, int n_in,
                              void* d_out, int out_size, void* d_ws, size_t ws_size,
                              hipStream_t stream) {
  (void)in_sizes; (void)n_in; (void)out_size;
  const float* h0  = (const float*)d_in[0];
  const float* c0  = (const float*)d_in[1];
  const float* xs  = (const float*)d_in[2];
  const float* Wii = (const float*)d_in[3];
  const float* bii = (const float*)d_in[4];
  const float* Whi = (const float*)d_in[5];
  const float* bhi = (const float*)d_in[6];
  const float* Wif = (const float*)d_in[7];
  const float* bif = (const float*)d_in[8];
  const float* Whf = (const float*)d_in[9];
  const float* bhf = (const float*)d_in[10];
  const float* Wig = (const float*)d_in[11];
  const float* big = (const float*)d_in[12];
  const float* Whg = (const float*)d_in[13];
  const float* bhg = (const float*)d_in[14];
  const float* Wio = (const float*)d_in[15];
  const float* bio = (const float*)d_in[16];
  const float* Who = (const float*)d_in[17];
  const float* bho = (const float*)d_in[18];

  // ws layout: WhT 2MB | WxT 2MB | bsum 8KB | hbuf 64KB | flags 128B  (~4.27MB)
  char* ws = (char*)d_ws;
  unsigned short* WhT  = (unsigned short*)ws;
  unsigned short* WxT  = (unsigned short*)(ws + (2u << 20));
  float*          bsum = (float*)(ws + (4u << 20));
  unsigned short* hbuf = (unsigned short*)(ws + (4u << 20) + 8192);
  int*            flags = (int*)(ws + (4u << 20) + 8192 + 65536);
  if (ws_size < (4u << 20) + 8192 + 65536 + 128) return;  // visible failure if ws too small

  const int total = 2048 * 512 + 2048 + 16384 + NWG;
  pack_kernel<<<(total + 255) / 256, 256, 0, stream>>>(
      h0, Wii, bii, Whi, bhi, Wif, bif, Whf, bhf,
      Wig, big, Whg, bhg, Wio, bio, Who, bho,
      WhT, WxT, bsum, hbuf, flags);
  lstm_scan<<<NWG, 256, 0, stream>>>(xs, c0, WhT, WxT, bsum, hbuf, flags, (float*)d_out);
}